// Round 4
// baseline (550.504 us; speedup 1.0000x reference)
//
#include <hip/hip_runtime.h>
#include <hip/hip_bf16.h>

// Problem: B=64, T=4096, D=256, CTX=100
//   logits[b,t] = tanh(X[b,t,:] @ W) @ u ; att = softmax_T(logits)
//   out[b,d]    = sum_t att[b,t] * X[b,t,d]
// Single pass over X (256 MiB); |logits| <= 5 so no max-shift needed.
// R4: R3 was latency-bound (52 VGPR -> compiler serialized all loads;
// 12.7k cyc/step). Now: explicit SW pipeline in registers (X depth-2,
// wfrag depth-1, fully unrolled K-loop, batched epilogue loads),
// launch_bounds(256,3), grid 2048.

#define NB 64
#define NT_TOK 4096
#define ND 256
#define NCTX 100
#define NTILE 7            // 7 x 16 = 112 >= 100 ctx columns (zero-padded)
#define KSTEPS 8           // 8 x 32 = 256 = D
#define BLOCKS_PER_B 32
#define NBLOCKS (NB * BLOCKS_PER_B)           // 2048
#define TOK_PER_BLOCK (NT_TOK / BLOCKS_PER_B) // 128
#define TILES_PER_WAVE 2   // 4 waves * 2 tiles * 16 tok = 128 tok/block

typedef __attribute__((ext_vector_type(8))) short short8;
typedef __attribute__((ext_vector_type(4))) float f32x4;

#define WS_UPAD_OFF 114688
#define WS_PNUM_OFF 115200
#define WS_PDEN_OFF (115200 + 2097152)

__device__ __forceinline__ unsigned short f2bf(float f) {
  unsigned u = __builtin_bit_cast(unsigned, f);
  u += 0x7FFFu + ((u >> 16) & 1u);          // round-to-nearest-even
  return (unsigned short)(u >> 16);
}

__device__ __forceinline__ float tanh_fast(float x) {
  float e = __expf(2.0f * x);
  return 1.0f - 2.0f / (e + 1.0f);
}

// wfrag[(nt*KSTEPS+s)*64 + lane][j] = bf16(W[32s + 8*(lane>>4) + j][16nt + (lane&15)])
// Same lane->k map used for A, so the HW's internal k permutation cancels.
__global__ void prep_kernel(const float* __restrict__ W, const float* __restrict__ u,
                            unsigned short* __restrict__ wfrag, float* __restrict__ upad) {
  int blk = blockIdx.x;    // 56
  int l = threadIdx.x;     // 64
  int nt = blk / KSTEPS, s = blk % KSTEPS;
  int col = nt * 16 + (l & 15);
  int kbase = s * 32 + (l >> 4) * 8;
  unsigned short v[8];
#pragma unroll
  for (int j = 0; j < 8; ++j) {
    float f = (col < NCTX) ? W[(size_t)(kbase + j) * NCTX + col] : 0.0f;
    v[j] = f2bf(f);
  }
  unsigned short* dst = wfrag + (size_t)(blk * 64 + l) * 8;
#pragma unroll
  for (int j = 0; j < 8; ++j) dst[j] = v[j];
  if (blk < 2) {
    int c = blk * 64 + l;
    if (c < NTILE * 16) upad[c] = (c < NCTX) ? u[c] : 0.0f;
  }
}

__global__ __launch_bounds__(256, 3) void main_kernel(
    const float* __restrict__ X, const unsigned short* __restrict__ wfrag,
    const float* __restrict__ upad, float* __restrict__ pnum, float* __restrict__ pden) {
  int blk = blockIdx.x;
  int b  = blk / BLOCKS_PER_B;
  int bi = blk % BLOCKS_PER_B;
  int tid = threadIdx.x;
  int wave = tid >> 6;
  int l  = tid & 63;
  int lg = l >> 4;   // k-chunk group 0..3
  int lr = l & 15;   // row (A) / col (B) within tile
  const float* Xb = X + (size_t)b * NT_TOK * ND;
  int tok_base = bi * TOK_PER_BLOCK + wave * (TILES_PER_WAVE * 16);

  float ucol[NTILE];
#pragma unroll
  for (int nt = 0; nt < NTILE; ++nt) ucol[nt] = upad[nt * 16 + lr];

  float accd[4] = {0.f, 0.f, 0.f, 0.f};
  float accden = 0.f;

  __shared__ float snum[4][ND];
  __shared__ float sden[4];

#pragma unroll 1
  for (int tile = 0; tile < TILES_PER_WAVE; ++tile) {
    int tok0 = tok_base + tile * 16;
    f32x4 c[NTILE];
#pragma unroll
    for (int nt = 0; nt < NTILE; ++nt) c[nt] = (f32x4){0.f, 0.f, 0.f, 0.f};

    const float* xrow = Xb + (size_t)(tok0 + lr) * ND + lg * 8;
    const unsigned short* wf_l = wfrag + (size_t)l * 8;

    // --- software pipeline: X depth-2, wfrag depth-1, full unroll ---
    f32x4 ax[3][2];     // rolling X buffers; all indices compile-time
    short8 bfb[2][NTILE];
    ax[0][0] = *(const f32x4*)(xrow + 0);
    ax[0][1] = *(const f32x4*)(xrow + 4);
    ax[1][0] = *(const f32x4*)(xrow + 32);
    ax[1][1] = *(const f32x4*)(xrow + 36);
#pragma unroll
    for (int nt = 0; nt < NTILE; ++nt)
      bfb[0][nt] = *(const short8*)(wf_l + (size_t)(nt * KSTEPS) * 512);

#pragma unroll
    for (int s = 0; s < KSTEPS; ++s) {
      const int cur = s % 3;
      const int far = (s + 2) % 3;
      const int bcur = s & 1;
      const int bnxt = (s + 1) & 1;
      // issue X loads 2 steps ahead (clamped; clamp hits L1, negligible)
      const int s2 = (s + 2 < KSTEPS) ? s + 2 : KSTEPS - 1;
      ax[far][0] = *(const f32x4*)(xrow + s2 * 32);
      ax[far][1] = *(const f32x4*)(xrow + s2 * 32 + 4);
      // issue wfrag loads 1 step ahead
      const int s1 = (s + 1 < KSTEPS) ? s + 1 : KSTEPS - 1;
#pragma unroll
      for (int nt = 0; nt < NTILE; ++nt)
        bfb[bnxt][nt] = *(const short8*)(wf_l + (size_t)(nt * KSTEPS + s1) * 512);
      // pack A fragment from current X
      short8 af;
      af[0] = (short)f2bf(ax[cur][0][0]); af[1] = (short)f2bf(ax[cur][0][1]);
      af[2] = (short)f2bf(ax[cur][0][2]); af[3] = (short)f2bf(ax[cur][0][3]);
      af[4] = (short)f2bf(ax[cur][1][0]); af[5] = (short)f2bf(ax[cur][1][1]);
      af[6] = (short)f2bf(ax[cur][1][2]); af[7] = (short)f2bf(ax[cur][1][3]);
#pragma unroll
      for (int nt = 0; nt < NTILE; ++nt)
        c[nt] = __builtin_amdgcn_mfma_f32_16x16x32_bf16(af, bfb[bcur][nt], c[nt], 0, 0, 0);
    }

    // logits: C/D layout (m89): reg j, lane l -> row=(l>>4)*4+j, col=l&15
    float sj[4];
#pragma unroll
    for (int j = 0; j < 4; ++j) {
      float t = 0.f;
#pragma unroll
      for (int nt = 0; nt < NTILE; ++nt) t = fmaf(tanh_fast(c[nt][j]), ucol[nt], t);
      sj[j] = t;
    }
#pragma unroll
    for (int j = 0; j < 4; ++j) {
      sj[j] += __shfl_xor(sj[j], 1, 64);
      sj[j] += __shfl_xor(sj[j], 2, 64);
      sj[j] += __shfl_xor(sj[j], 4, 64);
      sj[j] += __shfl_xor(sj[j], 8, 64);
    }
    float wj[4];
#pragma unroll
    for (int j = 0; j < 4; ++j) wj[j] = __expf(sj[j]);  // |logit| <= 5

    // broadcast all 16 row weights
    float wt[16];
#pragma unroll
    for (int t = 0; t < 16; ++t)
      wt[t] = __shfl(wj[t & 3], (t >> 2) * 16, 64);
#pragma unroll
    for (int t = 0; t < 16; ++t) accden += wt[t];

    // weighted accumulation, two batches of 8 independent loads (L2-hot)
    {
      f32x4 xv[8];
#pragma unroll
      for (int j = 0; j < 8; ++j)
        xv[j] = *(const f32x4*)(Xb + (size_t)(tok0 + j) * ND + l * 4);
#pragma unroll
      for (int j = 0; j < 8; ++j) {
        accd[0] = fmaf(wt[j], xv[j][0], accd[0]);
        accd[1] = fmaf(wt[j], xv[j][1], accd[1]);
        accd[2] = fmaf(wt[j], xv[j][2], accd[2]);
        accd[3] = fmaf(wt[j], xv[j][3], accd[3]);
      }
#pragma unroll
      for (int j = 0; j < 8; ++j)
        xv[j] = *(const f32x4*)(Xb + (size_t)(tok0 + 8 + j) * ND + l * 4);
#pragma unroll
      for (int j = 0; j < 8; ++j) {
        accd[0] = fmaf(wt[8 + j], xv[j][0], accd[0]);
        accd[1] = fmaf(wt[8 + j], xv[j][1], accd[1]);
        accd[2] = fmaf(wt[8 + j], xv[j][2], accd[2]);
        accd[3] = fmaf(wt[8 + j], xv[j][3], accd[3]);
      }
    }
  }

#pragma unroll
  for (int j = 0; j < 4; ++j) snum[wave][l * 4 + j] = accd[j];
  if (l == 0) sden[wave] = accden;
  __syncthreads();
  float s = snum[0][tid] + snum[1][tid] + snum[2][tid] + snum[3][tid];
  pnum[(size_t)blk * ND + tid] = s;
  if (tid == 0) pden[blk] = sden[0] + sden[1] + sden[2] + sden[3];
}

__global__ void fin_kernel(const float* __restrict__ pnum, const float* __restrict__ pden,
                           float* __restrict__ out) {
  int b = blockIdx.x;   // 64
  int d = threadIdx.x;  // 256
  float num = 0.f, den = 0.f;
#pragma unroll
  for (int i = 0; i < BLOCKS_PER_B; ++i) {
    num += pnum[(size_t)(b * BLOCKS_PER_B + i) * ND + d];
    den += pden[b * BLOCKS_PER_B + i];
  }
  out[b * ND + d] = num / den;
}

extern "C" void kernel_launch(void* const* d_in, const int* in_sizes, int n_in,
                              void* d_out, int out_size, void* d_ws, size_t ws_size,
                              hipStream_t stream) {
  const float* X = (const float*)d_in[0];
  const float* W = (const float*)d_in[1];
  const float* u = (const float*)d_in[2];
  float* out = (float*)d_out;
  char* ws = (char*)d_ws;
  unsigned short* wfrag = (unsigned short*)ws;
  float* upad = (float*)(ws + WS_UPAD_OFF);
  float* pnum = (float*)(ws + WS_PNUM_OFF);
  float* pden = (float*)(ws + WS_PDEN_OFF);

  hipLaunchKernelGGL(prep_kernel, dim3(NTILE * KSTEPS), dim3(64), 0, stream, W, u, wfrag, upad);
  hipLaunchKernelGGL(main_kernel, dim3(NBLOCKS), dim3(256), 0, stream, X, wfrag, upad, pnum, pden);
  hipLaunchKernelGGL(fin_kernel, dim3(NB), dim3(ND), 0, stream, pnum, pden, out);
}

// Round 5
// 443.549 us; speedup vs baseline: 1.2411x; 1.2411x over previous
//
#include <hip/hip_runtime.h>
#include <hip/hip_bf16.h>

// Problem: B=64, T=4096, D=256, CTX=100
//   logits[b,t] = tanh(X[b,t,:] @ W) @ u ; att = softmax_T(logits)
//   out[b,d]    = sum_t att[b,t] * X[b,t,d]
// Single pass over X (256 MiB); |logits| <= 5 so no max-shift needed.
// R5: R4's explicit reg-pipeline spilled to scratch (WRITE_SIZE 287 MB,
// rule #20). New structure: wfrag staged in LDS once per block (57 KB,
// ds_read_b128 conflict-free), K-loop fully unrolled straight-line so the
// compiler hoists X loads itself, launch_bounds(256,2) for a 256-VGPR
// budget (LDS caps occupancy at 2 blocks/CU regardless).

#define NB 64
#define NT_TOK 4096
#define ND 256
#define NCTX 100
#define NTILE 7            // 7 x 16 = 112 >= 100 ctx columns (zero-padded)
#define KSTEPS 8           // 8 x 32 = 256 = D
#define BLOCKS_PER_B 16
#define NBLOCKS (NB * BLOCKS_PER_B)           // 1024
#define TOK_PER_BLOCK (NT_TOK / BLOCKS_PER_B) // 256
#define TILES_PER_WAVE 4   // 4 waves * 4 tiles * 16 tok = 256 tok/block
#define WF_CHUNKS 3584     // 57344 B of wfrag as uint4

typedef __attribute__((ext_vector_type(8))) short short8;
typedef __attribute__((ext_vector_type(4))) float f32x4;

#define WS_UPAD_OFF 114688
#define WS_PNUM_OFF 115200
#define WS_PDEN_OFF (115200 + 1048576)

__device__ __forceinline__ unsigned short f2bf(float f) {
  unsigned u = __builtin_bit_cast(unsigned, f);
  u += 0x7FFFu + ((u >> 16) & 1u);          // round-to-nearest-even
  return (unsigned short)(u >> 16);
}

__device__ __forceinline__ short bfbits(float f) {
  __hip_bfloat16 h = __float2bfloat16(f);   // compiler fuses pairs to v_cvt_pk_bf16_f32
  return (short)__builtin_bit_cast(unsigned short, h);
}

__device__ __forceinline__ float tanh_fast(float x) {
  float e = __expf(2.0f * x);
  return 1.0f - 2.0f / (e + 1.0f);
}

// wfrag[(nt*KSTEPS+s)*64 + lane][j] = bf16(W[32s + 8*(lane>>4) + j][16nt + (lane&15)])
// Same lane->k map used for A, so the HW's internal k permutation cancels.
__global__ void prep_kernel(const float* __restrict__ W, const float* __restrict__ u,
                            unsigned short* __restrict__ wfrag, float* __restrict__ upad) {
  int blk = blockIdx.x;    // 56
  int l = threadIdx.x;     // 64
  int nt = blk / KSTEPS, s = blk % KSTEPS;
  int col = nt * 16 + (l & 15);
  int kbase = s * 32 + (l >> 4) * 8;
  unsigned short v[8];
#pragma unroll
  for (int j = 0; j < 8; ++j) {
    float f = (col < NCTX) ? W[(size_t)(kbase + j) * NCTX + col] : 0.0f;
    v[j] = f2bf(f);
  }
  unsigned short* dst = wfrag + (size_t)(blk * 64 + l) * 8;
#pragma unroll
  for (int j = 0; j < 8; ++j) dst[j] = v[j];
  if (blk < 2) {
    int c = blk * 64 + l;
    if (c < NTILE * 16) upad[c] = (c < NCTX) ? u[c] : 0.0f;
  }
}

__global__ __launch_bounds__(256, 2) void main_kernel(
    const float* __restrict__ X, const unsigned short* __restrict__ wfrag,
    const float* __restrict__ upad, float* __restrict__ pnum, float* __restrict__ pden) {
  int blk = blockIdx.x;
  int b  = blk / BLOCKS_PER_B;
  int bi = blk % BLOCKS_PER_B;
  int tid = threadIdx.x;
  int wave = tid >> 6;
  int l  = tid & 63;
  int lg = l >> 4;   // k-chunk group 0..3
  int lr = l & 15;   // row (A) / col (B) within tile

  __shared__ uint4 swf4[WF_CHUNKS];   // 57344 B: whole wfrag
  __shared__ float snum[4][ND];
  __shared__ float sden[4];

  // ---- stage wfrag into LDS (coalesced, once per block) ----
  {
    const uint4* g4 = (const uint4*)wfrag;
#pragma unroll
    for (int i = 0; i < WF_CHUNKS / 256; ++i)
      swf4[i * 256 + tid] = g4[i * 256 + tid];
  }
  __syncthreads();
  const unsigned short* swf = (const unsigned short*)swf4;
  const unsigned short* swf_l = swf + (size_t)l * 8;

  const float* Xb = X + (size_t)b * NT_TOK * ND;
  int tok_base = bi * TOK_PER_BLOCK + wave * (TILES_PER_WAVE * 16);

  float ucol[NTILE];
#pragma unroll
  for (int nt = 0; nt < NTILE; ++nt) ucol[nt] = upad[nt * 16 + lr];

  float accd[4] = {0.f, 0.f, 0.f, 0.f};
  float accden = 0.f;

#pragma unroll 1
  for (int tile = 0; tile < TILES_PER_WAVE; ++tile) {
    int tok0 = tok_base + tile * 16;
    f32x4 c[NTILE];
#pragma unroll
    for (int nt = 0; nt < NTILE; ++nt) c[nt] = (f32x4){0.f, 0.f, 0.f, 0.f};

    const float* xrow = Xb + (size_t)(tok0 + lr) * ND + lg * 8;

    // fully unrolled: compiler hoists the 16 independent global X loads
    // (HBM stream) while B-frags come cheap from LDS (lgkmcnt path)
#pragma unroll
    for (int s = 0; s < KSTEPS; ++s) {
      f32x4 a0 = *(const f32x4*)(xrow + s * 32);
      f32x4 a1 = *(const f32x4*)(xrow + s * 32 + 4);
      short8 af;
      af[0] = bfbits(a0[0]); af[1] = bfbits(a0[1]);
      af[2] = bfbits(a0[2]); af[3] = bfbits(a0[3]);
      af[4] = bfbits(a1[0]); af[5] = bfbits(a1[1]);
      af[6] = bfbits(a1[2]); af[7] = bfbits(a1[3]);
#pragma unroll
      for (int nt = 0; nt < NTILE; ++nt) {
        short8 bf = *(const short8*)(swf_l + (size_t)(nt * KSTEPS + s) * 512);
        c[nt] = __builtin_amdgcn_mfma_f32_16x16x32_bf16(af, bf, c[nt], 0, 0, 0);
      }
    }

    // logits: C/D layout (m89): reg j, lane l -> row=(l>>4)*4+j, col=l&15
    float sj[4];
#pragma unroll
    for (int j = 0; j < 4; ++j) {
      float t = 0.f;
#pragma unroll
      for (int nt = 0; nt < NTILE; ++nt) t = fmaf(tanh_fast(c[nt][j]), ucol[nt], t);
      sj[j] = t;
    }
#pragma unroll
    for (int j = 0; j < 4; ++j) {
      sj[j] += __shfl_xor(sj[j], 1, 64);
      sj[j] += __shfl_xor(sj[j], 2, 64);
      sj[j] += __shfl_xor(sj[j], 4, 64);
      sj[j] += __shfl_xor(sj[j], 8, 64);
    }
    float wj[4];
#pragma unroll
    for (int j = 0; j < 4; ++j) wj[j] = __expf(sj[j]);  // |logit| <= 5

    float wt[16];
#pragma unroll
    for (int t = 0; t < 16; ++t)
      wt[t] = __shfl(wj[t & 3], (t >> 2) * 16, 64);
#pragma unroll
    for (int t = 0; t < 16; ++t) accden += wt[t];

    // weighted accumulation: two batches of 8 independent cache-hot loads
    {
      f32x4 xv[8];
#pragma unroll
      for (int j = 0; j < 8; ++j)
        xv[j] = *(const f32x4*)(Xb + (size_t)(tok0 + j) * ND + l * 4);
#pragma unroll
      for (int j = 0; j < 8; ++j) {
        accd[0] = fmaf(wt[j], xv[j][0], accd[0]);
        accd[1] = fmaf(wt[j], xv[j][1], accd[1]);
        accd[2] = fmaf(wt[j], xv[j][2], accd[2]);
        accd[3] = fmaf(wt[j], xv[j][3], accd[3]);
      }
#pragma unroll
      for (int j = 0; j < 8; ++j)
        xv[j] = *(const f32x4*)(Xb + (size_t)(tok0 + 8 + j) * ND + l * 4);
#pragma unroll
      for (int j = 0; j < 8; ++j) {
        accd[0] = fmaf(wt[8 + j], xv[j][0], accd[0]);
        accd[1] = fmaf(wt[8 + j], xv[j][1], accd[1]);
        accd[2] = fmaf(wt[8 + j], xv[j][2], accd[2]);
        accd[3] = fmaf(wt[8 + j], xv[j][3], accd[3]);
      }
    }
  }

#pragma unroll
  for (int j = 0; j < 4; ++j) snum[wave][l * 4 + j] = accd[j];
  if (l == 0) sden[wave] = accden;
  __syncthreads();
  float s = snum[0][tid] + snum[1][tid] + snum[2][tid] + snum[3][tid];
  pnum[(size_t)blk * ND + tid] = s;
  if (tid == 0) pden[blk] = sden[0] + sden[1] + sden[2] + sden[3];
}

__global__ void fin_kernel(const float* __restrict__ pnum, const float* __restrict__ pden,
                           float* __restrict__ out) {
  int b = blockIdx.x;   // 64
  int d = threadIdx.x;  // 256
  float num = 0.f, den = 0.f;
#pragma unroll
  for (int i = 0; i < BLOCKS_PER_B; ++i) {
    num += pnum[(size_t)(b * BLOCKS_PER_B + i) * ND + d];
    den += pden[b * BLOCKS_PER_B + i];
  }
  out[b * ND + d] = num / den;
}

extern "C" void kernel_launch(void* const* d_in, const int* in_sizes, int n_in,
                              void* d_out, int out_size, void* d_ws, size_t ws_size,
                              hipStream_t stream) {
  const float* X = (const float*)d_in[0];
  const float* W = (const float*)d_in[1];
  const float* u = (const float*)d_in[2];
  float* out = (float*)d_out;
  char* ws = (char*)d_ws;
  unsigned short* wfrag = (unsigned short*)ws;
  float* upad = (float*)(ws + WS_UPAD_OFF);
  float* pnum = (float*)(ws + WS_PNUM_OFF);
  float* pden = (float*)(ws + WS_PDEN_OFF);

  hipLaunchKernelGGL(prep_kernel, dim3(NTILE * KSTEPS), dim3(64), 0, stream, W, u, wfrag, upad);
  hipLaunchKernelGGL(main_kernel, dim3(NBLOCKS), dim3(256), 0, stream, X, wfrag, upad, pnum, pden);
  hipLaunchKernelGGL(fin_kernel, dim3(NB), dim3(ND), 0, stream, pnum, pden, out);
}